// Round 5
// baseline (4796.155 us; speedup 1.0000x reference)
//
#include <hip/hip_runtime.h>
#include <hip/hip_bf16.h>
#include <cstdint>
#include <cstddef>

// MultiHeadAttention: B=4,S=2048,D=1024,H=16,DK=64, causal.
// Inputs fp32 (proven via round-1/2 NaN signature), output fp32 (reference
// output dtype; this round's single change). Pipeline: 3x proj GEMM ->
// flash attention -> out GEMM. VALU GEMM kept from round 4 (one variable
// at a time); MFMA GEMM is validated (round3 == round4 bit-identical) and
// returns once green.

namespace {

constexpr int B  = 4;
constexpr int S  = 2048;
constexpr int D  = 1024;
constexpr int H  = 16;
constexpr int DK = 64;
constexpr int M  = B * S;          // 8192 rows for projection GEMMs
constexpr float SM_SCALE = 0.125f; // 1/sqrt(DK)
constexpr float NEG_BIG  = -1e30f; // finite sentinel, matches reference NEG_INF

using bf16 = __hip_bfloat16;

__device__ __forceinline__ float bits2f(uint32_t lo16) {
  return __builtin_bit_cast(float, lo16 << 16);
}
__device__ __forceinline__ bf16 f2bf(float f) { return __float2bfloat16(f); }

// ---------------------------------------------------------------------------
// VALU GEMM: out = A[M,K] @ W[N,K]^T + bias; A fp32 or bf16, W/bias fp32,
// fp32 accumulate. OutT selects store dtype (float for d_out, bf16 for ws).
// 64x64 tile, 256 threads = 16x16, each thread a 4x4 micro-tile.
// MODE 0: row-major [M,N] store (final projection -> d_out, fp32)
// MODE 1: scatter to [B,H,S,DK] (row=(b,s), col=(h,dk)), bf16 ws
// ---------------------------------------------------------------------------
template <int MODE, bool A_IS_BF16, typename OutT>
__global__ __launch_bounds__(256)
void gemm_valu(const void* __restrict__ Av, const float* __restrict__ W,
               const float* __restrict__ bias, OutT* __restrict__ out,
               int Mtot, int N, int K)
{
  alignas(16) __shared__ float As[64][68]; // 68: row stride 272B (16B-aligned rows)
  alignas(16) __shared__ float Ws[64][68];

  const int tid = threadIdx.x;
  const int tx  = tid & 15;   // -> cols tx*4..+3
  const int ty  = tid >> 4;   // -> rows ty*4..+3

  const int row0 = blockIdx.y * 64, col0 = blockIdx.x * 64;

  float acc[4][4] = {};

  const int kTiles = K / 64;
  for (int kt = 0; kt < kTiles; ++kt) {
    __syncthreads();
    // stage 64x64 fp32 tiles: 1024 float4 chunks each, 4 per thread
#pragma unroll
    for (int i = 0; i < 4; ++i) {
      const int chunk = tid + i * 256;       // 0..1023
      const int r = chunk >> 4, c4 = chunk & 15;
      // W[N,K] rows are output cols
      {
        const float* src = W + (size_t)(col0 + r) * K + kt * 64 + c4 * 4;
        *(float4*)&Ws[r][c4 * 4] = *(const float4*)src;
      }
      if (A_IS_BF16) {
        const bf16* src = (const bf16*)Av + (size_t)(row0 + r) * K + kt * 64 + c4 * 4;
        const uint2 u = *(const uint2*)src; // 4 bf16
        As[r][c4 * 4 + 0] = bits2f(u.x & 0xffffu);
        As[r][c4 * 4 + 1] = bits2f(u.x >> 16);
        As[r][c4 * 4 + 2] = bits2f(u.y & 0xffffu);
        As[r][c4 * 4 + 3] = bits2f(u.y >> 16);
      } else {
        const float* src = (const float*)Av + (size_t)(row0 + r) * K + kt * 64 + c4 * 4;
        *(float4*)&As[r][c4 * 4] = *(const float4*)src;
      }
    }
    __syncthreads();

    for (int k4 = 0; k4 < 16; ++k4) {
      float4 a[4], b[4];
#pragma unroll
      for (int i = 0; i < 4; ++i) a[i] = *(const float4*)&As[ty * 4 + i][k4 * 4];
#pragma unroll
      for (int j = 0; j < 4; ++j) b[j] = *(const float4*)&Ws[tx * 4 + j][k4 * 4];
#pragma unroll
      for (int i = 0; i < 4; ++i)
#pragma unroll
        for (int j = 0; j < 4; ++j) {
          acc[i][j] = fmaf(a[i].x, b[j].x, acc[i][j]);
          acc[i][j] = fmaf(a[i].y, b[j].y, acc[i][j]);
          acc[i][j] = fmaf(a[i].z, b[j].z, acc[i][j]);
          acc[i][j] = fmaf(a[i].w, b[j].w, acc[i][j]);
        }
    }
  }

#pragma unroll
  for (int i = 0; i < 4; ++i) {
    const int row = row0 + ty * 4 + i;
#pragma unroll
    for (int j = 0; j < 4; ++j) {
      const int col = col0 + tx * 4 + j;
      const float v = acc[i][j] + bias[col];
      if (MODE == 0) {
        out[(size_t)row * N + col] = (OutT)v; // OutT=float: exact store
      } else {
        const int b_ = row >> 11, s_ = row & (S - 1);
        const int h_ = col >> 6,  dk = col & (DK - 1);
        out[(((size_t)b_ * H + h_) * S + s_) * DK + dk] = (OutT)v;
      }
    }
  }
}

// ---------------------------------------------------------------------------
// Flash attention (causal), vector ALU. Q,K,V: [B*H, S, DK] bf16 (from ws).
// Unchanged from rounds 3/4.
// ---------------------------------------------------------------------------
__global__ __launch_bounds__(256)
void flash_attn(const bf16* __restrict__ Q, const bf16* __restrict__ K,
                const bf16* __restrict__ V, bf16* __restrict__ ctx)
{
  __shared__ float Ks[64][65];
  __shared__ float Vs[64][65];

  const int tid  = threadIdx.x;
  const int w    = tid >> 6;
  const int lane = tid & 63;
  const int bh   = blockIdx.y;
  const int r    = blockIdx.x * 4 + w;
  const size_t base = (size_t)bh * S * DK;

  float qreg[DK];
  {
    const uint32_t* qrow = reinterpret_cast<const uint32_t*>(Q + base + (size_t)r * DK);
#pragma unroll
    for (int i = 0; i < DK / 2; ++i) {
      const uint32_t u = qrow[i];
      qreg[2 * i]     = bits2f(u & 0xffffu) * SM_SCALE;
      qreg[2 * i + 1] = bits2f(u >> 16) * SM_SCALE;
    }
  }

  float m_i = NEG_BIG, l_i = 0.f, o_acc = 0.f;

  const int nt = blockIdx.x / 16 + 1; // 64-key tiles covering k <= r0+3
  for (int t = 0; t < nt; ++t) {
    const int k0 = t * 64;
    __syncthreads();
    {
      const uint32_t* Kg = reinterpret_cast<const uint32_t*>(K + base + (size_t)k0 * DK);
      const uint32_t* Vg = reinterpret_cast<const uint32_t*>(V + base + (size_t)k0 * DK);
#pragma unroll
      for (int i = 0; i < 8; ++i) {
        const int idx = tid + i * 256; // 0..2047 uint32 (2 bf16 each)
        const int row = idx >> 5, c2 = idx & 31;
        const uint32_t ku = Kg[idx], vu = Vg[idx];
        Ks[row][2 * c2]     = bits2f(ku & 0xffffu);
        Ks[row][2 * c2 + 1] = bits2f(ku >> 16);
        Vs[row][2 * c2]     = bits2f(vu & 0xffffu);
        Vs[row][2 * c2 + 1] = bits2f(vu >> 16);
      }
    }
    __syncthreads();

    if (k0 <= r) {
      const bool valid = (k0 + lane <= r);
      float s = 0.f;
#pragma unroll
      for (int d = 0; d < DK; ++d) s = fmaf(qreg[d], Ks[lane][d], s);
      if (!valid) s = NEG_BIG;

      float mt = s;
#pragma unroll
      for (int off = 32; off; off >>= 1) mt = fmaxf(mt, __shfl_xor(mt, off));
      const float m_new = fmaxf(m_i, mt);
      const float p = valid ? __expf(s - m_new) : 0.f;
      float lt = p;
#pragma unroll
      for (int off = 32; off; off >>= 1) lt += __shfl_xor(lt, off);
      const float alpha = __expf(m_i - m_new);
      l_i = l_i * alpha + lt;
      m_i = m_new;

      o_acc *= alpha;
#pragma unroll
      for (int j = 0; j < 64; ++j) {
        const float pj = __shfl(p, j);
        o_acc = fmaf(pj, Vs[j][lane], o_acc);
      }
    }
  }

  const int b_ = bh >> 4, h_ = bh & (H - 1);
  const float o = o_acc / l_i;
  ctx[(((size_t)b_ * S + r) * H + h_) * DK + lane] = f2bf(o);
}

} // namespace

extern "C" void kernel_launch(void* const* d_in, const int* in_sizes, int n_in,
                              void* d_out, int out_size, void* d_ws, size_t ws_size,
                              hipStream_t stream)
{
  const float* query = (const float*)d_in[0];
  const float* key_  = (const float*)d_in[1];
  const float* value = (const float*)d_in[2];
  const float* Wq    = (const float*)d_in[3];
  const float* bq    = (const float*)d_in[4];
  const float* Wk    = (const float*)d_in[5];
  const float* bk    = (const float*)d_in[6];
  const float* Wv    = (const float*)d_in[7];
  const float* bv    = (const float*)d_in[8];
  const float* Wo    = (const float*)d_in[9];
  const float* bo    = (const float*)d_in[10];
  // d_in[11]: causal mask — applied analytically in flash_attn.

  const size_t qkv_elems = (size_t)B * H * S * DK; // 8,388,608
  bf16* q_ws = (bf16*)d_ws;
  bf16* k_ws = q_ws + qkv_elems;
  bf16* v_ws = k_ws + qkv_elems;
  bf16* ctx  = v_ws + qkv_elems;   // [B,S,H,DK]; total ws = 64 MiB

  const dim3 gproj(D / 64, M / 64); // (16, 128)
  gemm_valu<1, false, bf16><<<gproj, 256, 0, stream>>>(query, Wq, bq, q_ws, M, D, D);
  gemm_valu<1, false, bf16><<<gproj, 256, 0, stream>>>(key_,  Wk, bk, k_ws, M, D, D);
  gemm_valu<1, false, bf16><<<gproj, 256, 0, stream>>>(value, Wv, bv, v_ws, M, D, D);

  const dim3 gattn(S / 4, B * H);   // (512, 64)
  flash_attn<<<gattn, 256, 0, stream>>>(q_ws, k_ws, v_ws, ctx);

  // Final projection: fp32 store to d_out (reference output dtype).
  gemm_valu<0, true, float><<<gproj, 256, 0, stream>>>(ctx, Wo, bo, (float*)d_out, M, D, D);
}

// Round 6
// 614.302 us; speedup vs baseline: 7.8075x; 7.8075x over previous
//
#include <hip/hip_runtime.h>
#include <hip/hip_bf16.h>
#include <cstdint>
#include <cstddef>

// MultiHeadAttention: B=4,S=2048,D=1024,H=16,DK=64, causal.
// Inputs fp32, output fp32. All-MFMA pipeline:
//   3x proj GEMM (MFMA, V stored transposed) -> MFMA flash attention ->
//   out GEMM (MFMA, fp32 store).
// Fragment layouts (HW-verified, learn_hip m89/m91/m120):
//   A/B 16x16x32: [m|n = lane&15][k = (lane>>4)*8 + j]
//   C/D:          col = lane&15, row = (lane>>4)*4 + reg

namespace {

constexpr int B  = 4;
constexpr int S  = 2048;
constexpr int D  = 1024;
constexpr int H  = 16;
constexpr int DK = 64;
constexpr int M  = B * S;
constexpr float SM_SCALE = 0.125f; // 1/sqrt(DK)
constexpr float NEG_BIG  = -1e30f;

using bf16 = __hip_bfloat16;

typedef __attribute__((ext_vector_type(8))) __bf16 bf16x8;
typedef __attribute__((ext_vector_type(4))) float  f32x4;

__device__ __forceinline__ float bits2f(uint32_t lo16) {
  return __builtin_bit_cast(float, lo16 << 16);
}
__device__ __forceinline__ bf16 f2bf(float f) { return __float2bfloat16(f); }
// RNE fp32->bf16 bits
__device__ __forceinline__ uint16_t f2bfu(float x) {
  uint32_t a = __builtin_bit_cast(uint32_t, x);
  return (uint16_t)((a + 0x7FFFu + ((a >> 16) & 1u)) >> 16);
}
__device__ __forceinline__ uint32_t pk2(float x, float y) {
  return (uint32_t)f2bfu(x) | ((uint32_t)f2bfu(y) << 16);
}
__device__ __forceinline__ uint4 pack8(const float* p) {
  uint4 r;
  r.x = pk2(p[0], p[1]); r.y = pk2(p[2], p[3]);
  r.z = pk2(p[4], p[5]); r.w = pk2(p[6], p[7]);
  return r;
}

// ---------------------------------------------------------------------------
// MFMA GEMM: out = A[M,K] @ W[N,K]^T + bias; A fp32 or bf16, W/bias fp32.
// MODE 0: row-major [M,N] fp32 store (final projection -> d_out)
// MODE 1: bf16 scatter to [B,H,S,DK]   (q,k ws)
// MODE 2: bf16 scatter to [B,H,DK,S]   (V transposed, packed 8B stores)
// 64x64 tile, BK=64, 256 threads = 4 waves (each 32x32 = 2x2 MFMA 16x16x32).
// LDS: 8-bf16 chunks, chunk c of row m at m*8 + (c ^ (m&7)) (validated r3/r4).
// ---------------------------------------------------------------------------
template <int MODE, bool A_IS_BF16, typename OutT>
__global__ __launch_bounds__(256)
void gemm_bt(const void* __restrict__ Av, const float* __restrict__ W,
             const float* __restrict__ bias, OutT* __restrict__ out,
             int Mtot, int N, int K)
{
  __shared__ uint4 AsU[512]; // 64 rows x 8 chunks of 8 bf16
  __shared__ uint4 WsU[512];

  const int tid  = threadIdx.x;
  const int w    = tid >> 6;
  const int l    = tid & 63;
  const int lm   = l & 15;
  const int quad = l >> 4;
  const int wm   = (w >> 1) * 32;
  const int wn   = (w & 1) * 32;

  const int row0 = blockIdx.y * 64, col0 = blockIdx.x * 64;

  f32x4 acc[2][2] = {};

  const int kTiles = K / 64;
  for (int kt = 0; kt < kTiles; ++kt) {
    __syncthreads();
#pragma unroll
    for (int i = 0; i < 2; ++i) {
      const int idx = tid + i * 256;
      const int m = idx >> 3, c = idx & 7;
      const int dst = m * 8 + (c ^ (m & 7));
      {
        const float* src = W + (size_t)(col0 + m) * K + kt * 64 + c * 8;
        float tmp[8];
        *(float4*)tmp       = *(const float4*)src;
        *(float4*)(tmp + 4) = *(const float4*)(src + 4);
        WsU[dst] = pack8(tmp);
      }
      if (A_IS_BF16) {
        const bf16* src = (const bf16*)Av + (size_t)(row0 + m) * K + kt * 64 + c * 8;
        AsU[dst] = *(const uint4*)src;
      } else {
        const float* src = (const float*)Av + (size_t)(row0 + m) * K + kt * 64 + c * 8;
        float tmp[8];
        *(float4*)tmp       = *(const float4*)src;
        *(float4*)(tmp + 4) = *(const float4*)(src + 4);
        AsU[dst] = pack8(tmp);
      }
    }
    __syncthreads();
#pragma unroll
    for (int kk = 0; kk < 2; ++kk) {
      const int kc = kk * 4 + quad;
      const int sw = kc ^ (lm & 7);
      bf16x8 a0 = __builtin_bit_cast(bf16x8, AsU[(wm + lm) * 8 + sw]);
      bf16x8 a1 = __builtin_bit_cast(bf16x8, AsU[(wm + 16 + lm) * 8 + sw]);
      bf16x8 b0 = __builtin_bit_cast(bf16x8, WsU[(wn + lm) * 8 + sw]);
      bf16x8 b1 = __builtin_bit_cast(bf16x8, WsU[(wn + 16 + lm) * 8 + sw]);
      acc[0][0] = __builtin_amdgcn_mfma_f32_16x16x32_bf16(a0, b0, acc[0][0], 0, 0, 0);
      acc[0][1] = __builtin_amdgcn_mfma_f32_16x16x32_bf16(a0, b1, acc[0][1], 0, 0, 0);
      acc[1][0] = __builtin_amdgcn_mfma_f32_16x16x32_bf16(a1, b0, acc[1][0], 0, 0, 0);
      acc[1][1] = __builtin_amdgcn_mfma_f32_16x16x32_bf16(a1, b1, acc[1][1], 0, 0, 0);
    }
  }

#pragma unroll
  for (int tm = 0; tm < 2; ++tm) {
#pragma unroll
    for (int tn = 0; tn < 2; ++tn) {
      const int col = col0 + wn + tn * 16 + lm;
      const float bv = bias[col];
      if (MODE == 2) {
        // V^T: rows r are 4 consecutive s -> pack to one 8B store
        float vv[4];
#pragma unroll
        for (int r = 0; r < 4; ++r) vv[r] = acc[tm][tn][r] + bv;
        const int s0 = row0 + wm + tm * 16 + quad * 4;
        const int b_ = s0 >> 11, ss = s0 & (S - 1);
        const int h_ = col >> 6, dk = col & (DK - 1);
        uint2 st; st.x = pk2(vv[0], vv[1]); st.y = pk2(vv[2], vv[3]);
        *(uint2*)((bf16*)out + (((size_t)b_ * H + h_) * DK + dk) * S + ss) = st;
      } else {
#pragma unroll
        for (int r = 0; r < 4; ++r) {
          const int row = row0 + wm + tm * 16 + quad * 4 + r;
          const float v = acc[tm][tn][r] + bv;
          if (MODE == 0) {
            ((float*)out)[(size_t)row * N + col] = v;
          } else {
            const int b_ = row >> 11, s_ = row & (S - 1);
            const int h_ = col >> 6,  dk = col & (DK - 1);
            ((bf16*)out)[(((size_t)b_ * H + h_) * S + s_) * DK + dk] = f2bf(v);
          }
        }
      }
    }
  }
}

// ---------------------------------------------------------------------------
// MFMA flash attention (causal). Q,K: [B*H,S,DK] bf16; Vt: [B*H,DK,S] bf16.
// Block = 4 waves = 64 q rows of one (b,h); wave w owns q rows [w*16,w*16+16).
// Per 64-key tile: QK^T (A=Q regs, B=K LDS b128) -> in-wave row softmax ->
// P via per-wave LDS (C/D -> A layout) -> PV (B=Vt LDS b128) into AGPRs.
// Epilogue: O transposed through LDS -> coalesced 16B ctx stores.
// ---------------------------------------------------------------------------
__global__ __launch_bounds__(256)
void flash_mfma(const bf16* __restrict__ Q, const bf16* __restrict__ K,
                const bf16* __restrict__ Vt, bf16* __restrict__ ctx)
{
  __shared__ uint4 KsU[512];             // 64 keys x 64 dk, XOR-swizzled
  __shared__ uint4 VtU[512];             // 64 d   x 64 keys, XOR-swizzled
  __shared__ uint16_t PsAll[64 * 72];    // per-wave P / final O, stride 72 u16

  const int tid  = threadIdx.x;
  const int w    = tid >> 6;
  const int lane = tid & 63;
  const int lm   = lane & 15;
  const int quad = lane >> 4;
  const int bh   = blockIdx.y;
  const int qi   = blockIdx.x;           // q-tile index, 0..31
  const int q0   = qi * 64;
  const size_t base = (size_t)bh * S * DK;

  // Q A-fragments, held in registers all kernel: rows q0+w*16+lm
  bf16x8 qf[2];
  {
    const uint4* qp = (const uint4*)(Q + base + (size_t)(q0 + w * 16 + lm) * DK + quad * 8);
    qf[0] = __builtin_bit_cast(bf16x8, qp[0]);  // k = 0..31  (quad*8+j)
    qf[1] = __builtin_bit_cast(bf16x8, qp[4]);  // k = 32..63
  }

  uint16_t* Pw = PsAll + w * 16 * 72;
  const int qg = q0 + w * 16 + quad * 4;  // + r = this lane's C/D rows

  f32x4 o[4] = {};                        // [d-tile], C/D layout
  float m_i[4] = {NEG_BIG, NEG_BIG, NEG_BIG, NEG_BIG};
  float l_i[4] = {0.f, 0.f, 0.f, 0.f};

  const uint4* Kg = (const uint4*)(K + base);              // [key][dk]/8
  const uint4* Vg = (const uint4*)(Vt + (size_t)bh * DK * S); // [d][s]/8

  for (int t = 0; t <= qi; ++t) {
    const int k0 = t * 64;
    __syncthreads();
#pragma unroll
    for (int i = 0; i < 2; ++i) {
      const int idx = tid + i * 256;      // 0..511 chunks
      const int m = idx >> 3, c = idx & 7;
      const int dst = m * 8 + (c ^ (m & 7));
      KsU[dst] = Kg[(size_t)(k0 + m) * 8 + c];          // key row m
      VtU[dst] = Vg[(size_t)m * (S / 8) + k0 / 8 + c];  // d row m, keys k0..
    }
    __syncthreads();

    // ---- QK^T: scores for 16 q rows x 64 keys ----
    f32x4 sc[4];
#pragma unroll
    for (int tn = 0; tn < 4; ++tn) {
      sc[tn] = f32x4{0.f, 0.f, 0.f, 0.f};
      const int row = tn * 16 + lm;       // key index in tile
#pragma unroll
      for (int kf = 0; kf < 2; ++kf) {
        bf16x8 kb = __builtin_bit_cast(
            bf16x8, KsU[row * 8 + ((kf * 4 + quad) ^ (row & 7))]);
        sc[tn] = __builtin_amdgcn_mfma_f32_16x16x32_bf16(qf[kf], kb, sc[tn], 0, 0, 0);
      }
    }

    // scale + causal mask
#pragma unroll
    for (int tn = 0; tn < 4; ++tn) {
      const int kg = k0 + tn * 16 + lm;
#pragma unroll
      for (int r = 0; r < 4; ++r) {
        float v = sc[tn][r] * SM_SCALE;
        sc[tn][r] = (kg > qg + r) ? NEG_BIG : v;
      }
    }

    // ---- online softmax per q row (row = quad*4+r; reduce over lm group) ----
#pragma unroll
    for (int r = 0; r < 4; ++r) {
      float mr = fmaxf(fmaxf(sc[0][r], sc[1][r]), fmaxf(sc[2][r], sc[3][r]));
#pragma unroll
      for (int off = 8; off; off >>= 1) mr = fmaxf(mr, __shfl_xor(mr, off));
      const float mn = fmaxf(m_i[r], mr);
      const float al = __expf(m_i[r] - mn);   // ->0 on first tile
      float ls = 0.f;
#pragma unroll
      for (int tn = 0; tn < 4; ++tn) {
        const float p = __expf(sc[tn][r] - mn);  // masked: exp(-1e30)->0
        ls += p;
        Pw[(quad * 4 + r) * 72 + tn * 16 + lm] = f2bfu(p);
      }
#pragma unroll
      for (int off = 8; off; off >>= 1) ls += __shfl_xor(ls, off);
      l_i[r] = l_i[r] * al + ls;
      m_i[r] = mn;
#pragma unroll
      for (int tn = 0; tn < 4; ++tn) o[tn][r] *= al;
    }

    // ---- P (A layout) from own wave's LDS; PV ----
    bf16x8 ap[2];
    {
      const uint16_t* pr = Pw + lm * 72 + quad * 8;
      ap[0] = __builtin_bit_cast(bf16x8, *(const uint4*)pr);
      ap[1] = __builtin_bit_cast(bf16x8, *(const uint4*)(pr + 32));
    }
#pragma unroll
    for (int tn = 0; tn < 4; ++tn) {
      const int row = tn * 16 + lm;       // d index
#pragma unroll
      for (int kf = 0; kf < 2; ++kf) {
        bf16x8 vb = __builtin_bit_cast(
            bf16x8, VtU[row * 8 + ((kf * 4 + quad) ^ (row & 7))]);
        o[tn] = __builtin_amdgcn_mfma_f32_16x16x32_bf16(ap[kf], vb, o[tn], 0, 0, 0);
      }
    }
  }

  // ---- epilogue: normalize, transpose via LDS, coalesced store ----
  __syncthreads(); // protect PsAll reuse vs other waves' last-tile reads
#pragma unroll
  for (int r = 0; r < 4; ++r) {
    const float inv = 1.f / l_i[r];
#pragma unroll
    for (int tn = 0; tn < 4; ++tn)
      Pw[(quad * 4 + r) * 72 + tn * 16 + lm] = f2bfu(o[tn][r] * inv);
  }
  __syncthreads();

  const int b_ = bh >> 4, h_ = bh & (H - 1);
  const int row = tid >> 2, c16 = (tid & 3) * 16;
  const uint4* src = (const uint4*)(PsAll + row * 72 + c16);
  uint4* dst = (uint4*)(ctx + ((((size_t)b_ * S + q0 + row) * H + h_) << 6) + c16);
  dst[0] = src[0];
  dst[1] = src[1];
}

} // namespace

extern "C" void kernel_launch(void* const* d_in, const int* in_sizes, int n_in,
                              void* d_out, int out_size, void* d_ws, size_t ws_size,
                              hipStream_t stream)
{
  const float* query = (const float*)d_in[0];
  const float* key_  = (const float*)d_in[1];
  const float* value = (const float*)d_in[2];
  const float* Wq    = (const float*)d_in[3];
  const float* bq    = (const float*)d_in[4];
  const float* Wk    = (const float*)d_in[5];
  const float* bk    = (const float*)d_in[6];
  const float* Wv    = (const float*)d_in[7];
  const float* bv    = (const float*)d_in[8];
  const float* Wo    = (const float*)d_in[9];
  const float* bo    = (const float*)d_in[10];
  // d_in[11]: causal mask — applied analytically in flash_mfma.

  const size_t qkv_elems = (size_t)B * H * S * DK; // 8,388,608
  bf16* q_ws  = (bf16*)d_ws;
  bf16* k_ws  = q_ws + qkv_elems;
  bf16* vt_ws = k_ws + qkv_elems;  // [B,H,DK,S]
  bf16* ctx   = vt_ws + qkv_elems; // [B,S,D]; total ws = 64 MiB

  const dim3 gproj(D / 64, M / 64); // (16, 128)
  gemm_bt<1, false, bf16><<<gproj, 256, 0, stream>>>(query, Wq, bq, q_ws, M, D, D);
  gemm_bt<1, false, bf16><<<gproj, 256, 0, stream>>>(key_,  Wk, bk, k_ws, M, D, D);
  gemm_bt<2, false, bf16><<<gproj, 256, 0, stream>>>(value, Wv, bv, vt_ws, M, D, D);

  const dim3 gattn(S / 64, B * H);  // (32, 64)
  flash_mfma<<<gattn, 256, 0, stream>>>(q_ws, k_ws, vt_ws, ctx);

  gemm_bt<0, true, float><<<gproj, 256, 0, stream>>>(ctx, Wo, bo, (float*)d_out, M, D, D);
}

// Round 7
// 558.278 us; speedup vs baseline: 8.5910x; 1.1004x over previous
//
#include <hip/hip_runtime.h>
#include <hip/hip_bf16.h>
#include <cstdint>
#include <cstddef>

// MultiHeadAttention: B=4,S=2048,D=1024,H=16,DK=64, causal. fp32 in, fp32 out.
// Round 7: all-bf16 MFMA pipeline with hoisted dtype conversion.
//   cvt(q)+cvt(Wq) -> gemm128 -> ... -> flash v2 (128q-tile) -> gemm128 fp32 out
// gemm128 = m97-ladder structure: 128x128 tile, BK=64, global_load_lds(16B).
// Fragment layouts (HW-verified): A/B 16x16x32 [m|n=lane&15][k=quad*8+j];
// C/D col=lane&15, row=quad*4+reg.   (validated in rounds 3-6)

namespace {

constexpr int B  = 4;
constexpr int S  = 2048;
constexpr int D  = 1024;
constexpr int H  = 16;
constexpr int DK = 64;
constexpr int M  = B * S;
constexpr float SM_SCALE = 0.125f;
constexpr float NEG_BIG  = -1e30f;

using bf16 = __hip_bfloat16;

typedef __attribute__((ext_vector_type(8))) __bf16 bf16x8;
typedef __attribute__((ext_vector_type(4))) float  f32x4;

__device__ __forceinline__ uint16_t f2bfu(float x) { // RNE fp32->bf16 bits
  uint32_t a = __builtin_bit_cast(uint32_t, x);
  return (uint16_t)((a + 0x7FFFu + ((a >> 16) & 1u)) >> 16);
}
__device__ __forceinline__ uint32_t pk2(float x, float y) {
  return (uint32_t)f2bfu(x) | ((uint32_t)f2bfu(y) << 16);
}

// async 16B global -> LDS (wave-uniform LDS base + lane*16 implicit)
__device__ __forceinline__ void ldst16(const uint4* g, uint4* l) {
  __builtin_amdgcn_global_load_lds(
      (const __attribute__((address_space(1))) void*)g,
      (__attribute__((address_space(3))) void*)l, 16, 0, 0);
}

// ---------------------------------------------------------------------------
// fp32 -> bf16 bulk convert (memory-bound). n8 = elems/8.
// ---------------------------------------------------------------------------
__global__ __launch_bounds__(256)
void cvt_f2b(const float* __restrict__ src, bf16* __restrict__ dst, int n8)
{
  const int i = blockIdx.x * 256 + threadIdx.x;
  if (i >= n8) return;
  const float4 a = ((const float4*)src)[2 * i];
  const float4 b = ((const float4*)src)[2 * i + 1];
  uint4 r;
  r.x = pk2(a.x, a.y); r.y = pk2(a.z, a.w);
  r.z = pk2(b.x, b.y); r.w = pk2(b.z, b.w);
  ((uint4*)dst)[i] = r;
}

// ---------------------------------------------------------------------------
// gemm128: out = A[M,K](bf16) @ Wb[N,K](bf16)^T + bias(fp32).
// 128x128 tile, BK=64, 256 thr = 4 waves (2x2), each wave 64x64 = 4x4 MFMA.
// Staging via global_load_lds width=16, linear LDS (m97 structure).
// MODE 0: fp32 [M,N] store  MODE 1: bf16 [B,H,S,DK]  MODE 2: bf16 [B,H,DK,S]
// ---------------------------------------------------------------------------
template <int MODE>
__global__ __launch_bounds__(256)
void gemm128(const bf16* __restrict__ A, const bf16* __restrict__ Wb,
             const float* __restrict__ bias, void* __restrict__ out,
             int N, int K)
{
  __shared__ uint4 AsU[1024]; // 128 rows x 8 chunks (16KB)
  __shared__ uint4 BsU[1024];

  const int tid  = threadIdx.x;
  const int w    = tid >> 6;
  const int lane = tid & 63;
  const int lm   = lane & 15;
  const int quad = lane >> 4;
  const int wm   = (w >> 1) * 64;
  const int wn   = (w & 1) * 64;

  const int row0 = blockIdx.y * 128, col0 = blockIdx.x * 128;
  const int g8 = K >> 3; // uint4 per row

  const uint4* Ag = (const uint4*)A + (size_t)row0 * g8;
  const uint4* Bg = (const uint4*)Wb + (size_t)col0 * g8;

  f32x4 acc[4][4] = {};

  for (int kt = 0; kt < K / 64; ++kt) {
    __syncthreads();
#pragma unroll
    for (int i = 0; i < 4; ++i) {
      const int chunk = i * 256 + w * 64 + lane; // 0..1023
      const int r = chunk >> 3, c = chunk & 7;
      ldst16(&Ag[(size_t)r * g8 + kt * 8 + c], &AsU[i * 256 + w * 64]);
      ldst16(&Bg[(size_t)r * g8 + kt * 8 + c], &BsU[i * 256 + w * 64]);
    }
    __syncthreads();
#pragma unroll
    for (int kk = 0; kk < 2; ++kk) {
      bf16x8 af[4], bfr[4];
#pragma unroll
      for (int tm = 0; tm < 4; ++tm)
        af[tm] = __builtin_bit_cast(bf16x8, AsU[(wm + tm * 16 + lm) * 8 + kk * 4 + quad]);
#pragma unroll
      for (int tn = 0; tn < 4; ++tn)
        bfr[tn] = __builtin_bit_cast(bf16x8, BsU[(wn + tn * 16 + lm) * 8 + kk * 4 + quad]);
#pragma unroll
      for (int tm = 0; tm < 4; ++tm)
#pragma unroll
        for (int tn = 0; tn < 4; ++tn)
          acc[tm][tn] = __builtin_amdgcn_mfma_f32_16x16x32_bf16(af[tm], bfr[tn], acc[tm][tn], 0, 0, 0);
    }
  }

#pragma unroll
  for (int tm = 0; tm < 4; ++tm) {
#pragma unroll
    for (int tn = 0; tn < 4; ++tn) {
      const int col = col0 + wn + tn * 16 + lm;
      const float bv = bias[col];
      if (MODE == 2) {
        float vv[4];
#pragma unroll
        for (int r = 0; r < 4; ++r) vv[r] = acc[tm][tn][r] + bv;
        const int s0 = row0 + wm + tm * 16 + quad * 4;
        const int b_ = s0 >> 11, ss = s0 & (S - 1);
        const int h_ = col >> 6, dk = col & (DK - 1);
        uint2 st; st.x = pk2(vv[0], vv[1]); st.y = pk2(vv[2], vv[3]);
        *(uint2*)((bf16*)out + (((size_t)b_ * H + h_) * DK + dk) * S + ss) = st;
      } else {
#pragma unroll
        for (int r = 0; r < 4; ++r) {
          const int row = row0 + wm + tm * 16 + quad * 4 + r;
          const float v = acc[tm][tn][r] + bv;
          if (MODE == 0) {
            ((float*)out)[(size_t)row * N + col] = v;
          } else {
            const int b_ = row >> 11, s_ = row & (S - 1);
            const int h_ = col >> 6,  dk = col & (DK - 1);
            ((bf16*)out)[(((size_t)b_ * H + h_) * S + s_) * DK + dk] =
                __builtin_bit_cast(bf16, f2bfu(v));
          }
        }
      }
    }
  }
}

// ---------------------------------------------------------------------------
// flash v2 (causal MFMA). Q,K: [B*H,S,DK] bf16; Vt: [B*H,DK,S] bf16.
// Block = 4 waves, q-tile = 128 rows; wave w owns rows {g*64 + w*16 + [0,16)}
// for g in {0,1}. Per 64-key tile: QK^T -> online softmax (max reduced
// in-loop, row-sum deferred to epilogue) -> P via per-wave LDS -> PV.
// K/V staged via global_load_lds; per-(wave,group) causal skip.
// ---------------------------------------------------------------------------
__global__ __launch_bounds__(256)
void flash_mfma(const bf16* __restrict__ Q, const bf16* __restrict__ K,
                const bf16* __restrict__ Vt, bf16* __restrict__ ctx)
{
  __shared__ uint4 KsU[512];             // 64 keys x 64 dk (8KB)
  __shared__ uint4 VtU[512];             // 64 d x 64 keys (8KB)
  __shared__ uint16_t PsAll[128 * 72];   // P / final O, stride 72 u16 (18KB)

  const int tid  = threadIdx.x;
  const int w    = tid >> 6;
  const int lane = tid & 63;
  const int lm   = lane & 15;
  const int quad = lane >> 4;
  const int bh   = blockIdx.y;
  const int qi   = blockIdx.x;           // 0..15
  const int q0   = qi * 128;
  const size_t base = (size_t)bh * S * DK;

  // Q A-fragments for both row groups
  bf16x8 qf[2][2];
#pragma unroll
  for (int g = 0; g < 2; ++g) {
    const bf16* qrow = Q + base + (size_t)(q0 + g * 64 + w * 16 + lm) * DK;
    qf[g][0] = __builtin_bit_cast(bf16x8, *(const uint4*)(qrow + quad * 8));
    qf[g][1] = __builtin_bit_cast(bf16x8, *(const uint4*)(qrow + 32 + quad * 8));
  }

  f32x4 o[2][4] = {};
  float m_i[2][4], l_i[2][4];
#pragma unroll
  for (int g = 0; g < 2; ++g)
#pragma unroll
    for (int r = 0; r < 4; ++r) { m_i[g][r] = NEG_BIG; l_i[g][r] = 0.f; }

  const uint4* Kg = (const uint4*)(K + base);
  const uint4* Vg = (const uint4*)(Vt + (size_t)bh * DK * S);

  const int nt = 2 * qi + 2;
  for (int t = 0; t < nt; ++t) {
    const int k0 = t * 64;
    __syncthreads();
    {
      const int chunk = w * 64 + lane;       // 0..255 (first half)
      const int r0 = chunk >> 3, c0 = chunk & 7;
      ldst16(&Kg[(size_t)(k0 + r0) * 8 + c0], &KsU[w * 64]);
      ldst16(&Vg[(size_t)r0 * (S / 8) + k0 / 8 + c0], &VtU[w * 64]);
      const int chunk2 = 256 + chunk;
      const int r1 = chunk2 >> 3, c1 = chunk2 & 7;
      ldst16(&Kg[(size_t)(k0 + r1) * 8 + c1], &KsU[256 + w * 64]);
      ldst16(&Vg[(size_t)r1 * (S / 8) + k0 / 8 + c1], &VtU[256 + w * 64]);
    }
    __syncthreads();

#pragma unroll
    for (int g = 0; g < 2; ++g) {
      const int qbase = q0 + g * 64 + w * 16;
      if (k0 > qbase + 15) continue;       // wave-uniform causal skip
      uint16_t* Pw = PsAll + (g * 64 + w * 16) * 72;
      const int qg = qbase + quad * 4;

      // QK^T
      f32x4 sc[4];
#pragma unroll
      for (int tn = 0; tn < 4; ++tn) {
        sc[tn] = f32x4{0.f, 0.f, 0.f, 0.f};
        const int row = tn * 16 + lm;
#pragma unroll
        for (int kf = 0; kf < 2; ++kf) {
          bf16x8 kb = __builtin_bit_cast(bf16x8, KsU[row * 8 + kf * 4 + quad]);
          sc[tn] = __builtin_amdgcn_mfma_f32_16x16x32_bf16(qf[g][kf], kb, sc[tn], 0, 0, 0);
        }
      }
      // scale + causal mask
#pragma unroll
      for (int tn = 0; tn < 4; ++tn) {
        const int kg = k0 + tn * 16 + lm;
#pragma unroll
        for (int r = 0; r < 4; ++r) {
          const float v = sc[tn][r] * SM_SCALE;
          sc[tn][r] = (kg > qg + r) ? NEG_BIG : v;
        }
      }
      // online softmax: max reduced now, sum kept lane-partial
#pragma unroll
      for (int r = 0; r < 4; ++r) {
        float mr = fmaxf(fmaxf(sc[0][r], sc[1][r]), fmaxf(sc[2][r], sc[3][r]));
#pragma unroll
        for (int off = 8; off; off >>= 1) mr = fmaxf(mr, __shfl_xor(mr, off));
        const float mn = fmaxf(m_i[g][r], mr);
        const float al = __expf(m_i[g][r] - mn);
        float ls = 0.f;
#pragma unroll
        for (int tn = 0; tn < 4; ++tn) {
          const float p = __expf(sc[tn][r] - mn);
          ls += p;
          Pw[(quad * 4 + r) * 72 + tn * 16 + lm] = f2bfu(p);
        }
        l_i[g][r] = l_i[g][r] * al + ls;   // lane-partial (reduced at end)
        m_i[g][r] = mn;
#pragma unroll
        for (int tn = 0; tn < 4; ++tn) o[g][tn][r] *= al;
      }
      // P -> A-frags (own wave's LDS), PV
      bf16x8 ap[2];
      {
        const uint16_t* pr = Pw + lm * 72 + quad * 8;
        ap[0] = __builtin_bit_cast(bf16x8, *(const uint4*)pr);
        ap[1] = __builtin_bit_cast(bf16x8, *(const uint4*)(pr + 32));
      }
#pragma unroll
      for (int tn = 0; tn < 4; ++tn) {
        const int row = tn * 16 + lm;      // d index
#pragma unroll
        for (int kf = 0; kf < 2; ++kf) {
          bf16x8 vb = __builtin_bit_cast(bf16x8, VtU[row * 8 + kf * 4 + quad]);
          o[g][tn] = __builtin_amdgcn_mfma_f32_16x16x32_bf16(ap[kf], vb, o[g][tn], 0, 0, 0);
        }
      }
    }
  }

  // epilogue: reduce l, normalize, stash O in PsAll, coalesced store
  __syncthreads();
#pragma unroll
  for (int g = 0; g < 2; ++g) {
    uint16_t* Pw = PsAll + (g * 64 + w * 16) * 72;
#pragma unroll
    for (int r = 0; r < 4; ++r) {
      float lr = l_i[g][r];
#pragma unroll
      for (int off = 8; off; off >>= 1) lr += __shfl_xor(lr, off);
      const float inv = 1.f / lr;
#pragma unroll
      for (int tn = 0; tn < 4; ++tn)
        Pw[(quad * 4 + r) * 72 + tn * 16 + lm] = f2bfu(o[g][tn][r] * inv);
    }
  }
  __syncthreads();

  const int b_ = bh >> 4, h_ = bh & (H - 1);
#pragma unroll
  for (int i = 0; i < 4; ++i) {
    const int idx = tid + i * 256;         // 0..1023 uint4
    const int row = idx >> 3, c = idx & 7;
    const uint4 v = *(const uint4*)(PsAll + row * 72 + c * 8);
    *(uint4*)(ctx + ((((size_t)b_ * S + q0 + row) * H + h_) << 6) + c * 8) = v;
  }
}

} // namespace

extern "C" void kernel_launch(void* const* d_in, const int* in_sizes, int n_in,
                              void* d_out, int out_size, void* d_ws, size_t ws_size,
                              hipStream_t stream)
{
  const float* query = (const float*)d_in[0];
  const float* key_  = (const float*)d_in[1];
  const float* value = (const float*)d_in[2];
  const float* Wq    = (const float*)d_in[3];
  const float* bq    = (const float*)d_in[4];
  const float* Wk    = (const float*)d_in[5];
  const float* bk    = (const float*)d_in[6];
  const float* Wv    = (const float*)d_in[7];
  const float* bv    = (const float*)d_in[8];
  const float* Wo    = (const float*)d_in[9];
  const float* bo    = (const float*)d_in[10];
  // d_in[11]: causal mask — applied analytically in flash_mfma.

  const size_t qkv = (size_t)B * H * S * DK; // 8,388,608 elems
  bf16* slot0 = (bf16*)d_ws;        // q_ws; later Wo_bf
  bf16* slot1 = slot0 + qkv;        // k_ws
  bf16* slot2 = slot1 + qkv;        // vt_ws [B,H,DK,S]
  bf16* slot3 = slot2 + qkv;        // weight scratch, then ctx [B,S,D]
  bf16* inbf  = (bf16*)d_out;       // 16.8MB input-conversion scratch
                                    // (d_out fully rewritten by final GEMM)

  const int n8in = (int)(qkv / 8);          // 1048576
  const int n8w  = (D * D) / 8;             // 131072
  const dim3 cvtIn(n8in / 256), cvtW(n8w / 256);
  const dim3 gproj(D / 128, M / 128);       // (8, 64)
  const dim3 gattn(S / 128, B * H);         // (16, 64)

  // Q
  cvt_f2b<<<cvtIn, 256, 0, stream>>>(query, inbf, n8in);
  cvt_f2b<<<cvtW,  256, 0, stream>>>(Wq, slot3, n8w);
  gemm128<1><<<gproj, 256, 0, stream>>>(inbf, slot3, bq, slot0, D, D);
  // K
  cvt_f2b<<<cvtIn, 256, 0, stream>>>(key_, inbf, n8in);
  cvt_f2b<<<cvtW,  256, 0, stream>>>(Wk, slot3, n8w);
  gemm128<1><<<gproj, 256, 0, stream>>>(inbf, slot3, bk, slot1, D, D);
  // V (transposed output)
  cvt_f2b<<<cvtIn, 256, 0, stream>>>(value, inbf, n8in);
  cvt_f2b<<<cvtW,  256, 0, stream>>>(Wv, slot3, n8w);
  gemm128<2><<<gproj, 256, 0, stream>>>(inbf, slot3, bv, slot2, D, D);
  // attention -> ctx (overwrites weight scratch in slot3)
  flash_mfma<<<gattn, 256, 0, stream>>>(slot0, slot1, slot2, slot3);
  // output projection (fp32 store); Wo_bf stashed in dead slot0
  cvt_f2b<<<cvtW, 256, 0, stream>>>(Wo, slot0, n8w);
  gemm128<0><<<gproj, 256, 0, stream>>>(slot3, slot0, bo, d_out, D, D);
}